// Round 2
// baseline (860.127 us; speedup 1.0000x reference)
//
#include <hip/hip_runtime.h>
#include <hip/hip_bf16.h>
#include <cstddef>
#include <cstdint>

#define N_NODES 20000
#define N_EDGES 100000
#define N_BATCH 512

typedef __attribute__((ext_vector_type(8))) short bf16x8;
typedef __attribute__((ext_vector_type(4))) float f32x4;

__device__ __forceinline__ float sigmoidf_(float x) { return 1.f / (1.f + expf(-x)); }
__device__ __forceinline__ unsigned short f2bf(float x) {
    unsigned int u = __float_as_uint(x);
    unsigned int r = (u + 0x7fffu + ((u >> 16) & 1u)) >> 16;
    return (unsigned short)r;
}
__device__ __forceinline__ float bf2f(unsigned short s) {
    return __uint_as_float(((unsigned int)s) << 16);
}
__device__ __forceinline__ bf16x8 zero8() { bf16x8 z = {0,0,0,0,0,0,0,0}; return z; }

// ---------------- degree (edge count per dst) ----------------
__global__ void deg_kernel(const int* __restrict__ ei, float* __restrict__ deg, int E) {
    int e = blockIdx.x * 256 + threadIdx.x;
    if (e < E) atomicAdd(&deg[ei[E + e]], 1.0f);
}

// ---------------- h = relu(edge_attr @ nn1_w + nn1_b) -> bf16 [E,128] ----------------
__global__ void hidden_kernel(const float* __restrict__ ea, const float* __restrict__ w1,
                              const float* __restrict__ b1, unsigned short* __restrict__ hb) {
    int idx = blockIdx.x * 256 + threadIdx.x;   // e*128 + j
    int e = idx >> 7, j = idx & 127;
    float acc = b1[j];
#pragma unroll
    for (int i = 0; i < 8; i++) acc += ea[e * 8 + i] * w1[i * 128 + j];
    hb[idx] = f2bf(fmaxf(acc, 0.f));
}

// ---------------- pack W2 (+bias slot) into MFMA-B-fragment order ----------------
// Bsw[ks][oc][lane][j] = bf16( W2v[ks*32 + 8*(lane>>4)+j , oc*16 + (lane&15)] )
// W2v[kap, o] = W2flat[kap*64 + o] for kap < 8192; kap in [8192,8256) -> nn2_b
__global__ void bsw_pack(const float* __restrict__ w2, const float* __restrict__ b2,
                         unsigned short* __restrict__ bsw) {
    int idx = blockIdx.x * 256 + threadIdx.x;   // (ks*4+oc)*64 + l ; total 258*4*64=66048
    if (idx >= 66048) return;
    int l = idx & 63, oc = (idx >> 6) & 3, ks = idx >> 8;
    int o = oc * 16 + (l & 15);
    int kap0 = ks * 32 + 8 * (l >> 4);
#pragma unroll
    for (int j = 0; j < 8; ++j) {
        int kap = kap0 + j;            // kap = k*64 + i
        int k = kap >> 6, i = kap & 63;
        float v = (k < 128) ? w2[(size_t)k * 4096 + i * 64 + o] : b2[i * 64 + o];
        bsw[(size_t)idx * 8 + j] = f2bf(v);
    }
}

// ---------------- out = relu(x @ lin0_w + lin0_b) [N,64] ----------------
__global__ void lin0_kernel(const float* __restrict__ x, const float* __restrict__ w,
                            const float* __restrict__ b, float* __restrict__ out) {
    int idx = blockIdx.x * 256 + threadIdx.x;  // n*64 + j
    int n = idx >> 6, j = idx & 63;
    float acc = b[j];
#pragma unroll
    for (int i = 0; i < 16; i++) acc += x[n * 16 + i] * w[i * 64 + j];
    out[idx] = fmaxf(acc, 0.f);
}

// ---------------- fused NNConv message: msg = sum_k h[e,k]*(s_e @ B_k) + s_e @ b2v ----
// 1 wave/block, 64 edges/wave (4 row-tiles of 16), N=64 outs (4 chunks of 16).
__global__ __launch_bounds__(64) void msg_mfma(const float* __restrict__ out,
                                               const unsigned short* __restrict__ hb,
                                               const unsigned short* __restrict__ bsw,
                                               const int* __restrict__ ei,
                                               float* __restrict__ agg, int E) {
    __shared__ __align__(16) unsigned short hT[129 * 64];
    const int l = threadIdx.x;
    const int e0 = blockIdx.x * 64;
    const int r16 = l & 15, q = l >> 4;

    // stage hT transposed: hT[k][le] ; bias slot hT[128][le]=1
    {
        int e = e0 + l;
        bool v = e < E;
        const bf16x8* hrow = (const bf16x8*)(hb + (size_t)e * 128);
        for (int c = 0; c < 16; ++c) {
            bf16x8 hv = v ? hrow[c] : zero8();
#pragma unroll
            for (int j = 0; j < 8; ++j) hT[(c * 8 + j) * 64 + l] = (unsigned short)hv[j];
        }
        hT[128 * 64 + l] = v ? (unsigned short)0x3f80 : (unsigned short)0;
    }
    __syncthreads();

    // A fragments: s = out[src[e]] in bf16, fixed for whole k-loop
    bf16x8 sfrag[4][2];
#pragma unroll
    for (int t = 0; t < 4; ++t) {
        int e = e0 + t * 16 + r16;
        int src = (e < E) ? ei[e] : 0;
        const float* srow = out + (size_t)src * 64;
#pragma unroll
        for (int st = 0; st < 2; ++st) {
            bf16x8 f = zero8();
            if (e < E) {
                const float4* p = (const float4*)(srow + st * 32 + q * 8);
                float4 a = p[0], b = p[1];
                f[0] = f2bf(a.x); f[1] = f2bf(a.y); f[2] = f2bf(a.z); f[3] = f2bf(a.w);
                f[4] = f2bf(b.x); f[5] = f2bf(b.y); f[6] = f2bf(b.z); f[7] = f2bf(b.w);
            }
            sfrag[t][st] = f;
        }
    }

    f32x4 acc[4][4] = {};
    const bf16x8* bp = (const bf16x8*)bsw;
    for (int k = 0; k < 129; ++k) {
        bf16x8 bf[2][4];
#pragma unroll
        for (int st = 0; st < 2; ++st)
#pragma unroll
            for (int oc = 0; oc < 4; ++oc)
                bf[st][oc] = bp[((size_t)((k * 2 + st) * 4 + oc) << 6) + l];
#pragma unroll
        for (int t = 0; t < 4; ++t) {
            ushort4 hq = *(const ushort4*)&hT[k * 64 + t * 16 + q * 4];
            float h0 = bf2f(hq.x), h1 = bf2f(hq.y), h2 = bf2f(hq.z), h3 = bf2f(hq.w);
#pragma unroll
            for (int oc = 0; oc < 4; ++oc) {
                f32x4 T = {0.f, 0.f, 0.f, 0.f};
                T = __builtin_amdgcn_mfma_f32_16x16x32_bf16(sfrag[t][0], bf[0][oc], T, 0, 0, 0);
                T = __builtin_amdgcn_mfma_f32_16x16x32_bf16(sfrag[t][1], bf[1][oc], T, 0, 0, 0);
                acc[t][oc][0] += h0 * T[0];
                acc[t][oc][1] += h1 * T[1];
                acc[t][oc][2] += h2 * T[2];
                acc[t][oc][3] += h3 * T[3];
            }
        }
    }

    // scatter-add to agg[dst]
#pragma unroll
    for (int t = 0; t < 4; ++t) {
#pragma unroll
        for (int r = 0; r < 4; ++r) {
            int e = e0 + t * 16 + q * 4 + r;
            if (e < E) {
                int dst = ei[E + e];
                float* arow = agg + (size_t)dst * 64 + r16;
#pragma unroll
                for (int oc = 0; oc < 4; ++oc)
                    atomicAdd(arow + oc * 16, acc[t][oc][r]);
            }
        }
    }
}

// ---------------- m = relu(agg/deg + out@root_w + root_b); GRU(h=out, m) -> out ------
__global__ __launch_bounds__(256) void gru_kernel(float* __restrict__ out,
                                                  const float* __restrict__ agg,
                                                  const float* __restrict__ deg,
                                                  const float* __restrict__ root_w,
                                                  const float* __restrict__ root_b,
                                                  const float* __restrict__ wih,
                                                  const float* __restrict__ whh,
                                                  const float* __restrict__ bih,
                                                  const float* __restrict__ bhh) {
    int w = threadIdx.x >> 6, j = threadIdx.x & 63;
    int n = blockIdx.x * 4 + w;            // N divisible by 4
    __shared__ float s_o[4][64];
    __shared__ float s_m[4][64];
    s_o[w][j] = out[(size_t)n * 64 + j];
    __syncthreads();
    float d = deg[n]; if (d < 1.f) d = 1.f;
    float mv = agg[(size_t)n * 64 + j] / d + root_b[j];
#pragma unroll 8
    for (int i = 0; i < 64; i++) mv += s_o[w][i] * root_w[i * 64 + j];
    mv = fmaxf(mv, 0.f);
    s_m[w][j] = mv;
    __syncthreads();
    float gi_r = bih[j], gi_z = bih[64 + j], gi_n = bih[128 + j];
    float gh_r = bhh[j], gh_z = bhh[64 + j], gh_n = bhh[128 + j];
#pragma unroll 4
    for (int i = 0; i < 64; i++) {
        float m = s_m[w][i], hv = s_o[w][i];
        gi_r += m * wih[i * 192 + j];
        gi_z += m * wih[i * 192 + 64 + j];
        gi_n += m * wih[i * 192 + 128 + j];
        gh_r += hv * whh[i * 192 + j];
        gh_z += hv * whh[i * 192 + 64 + j];
        gh_n += hv * whh[i * 192 + 128 + j];
    }
    float r = sigmoidf_(gi_r + gh_r);
    float z = sigmoidf_(gi_z + gh_z);
    float nn = tanhf(gi_n + r * gh_n);
    float hnew = (1.f - z) * nn + z * s_o[w][j];
    out[(size_t)n * 64 + j] = hnew;
}

// ---------------- Set2Set LSTM cell (one wave per batch elem) ----------------
__global__ __launch_bounds__(256) void lstm_kernel(float* __restrict__ qstar,
                                                   float* __restrict__ hh, float* __restrict__ cc,
                                                   const float* __restrict__ wih,
                                                   const float* __restrict__ whh,
                                                   const float* __restrict__ bih,
                                                   const float* __restrict__ bhh) {
    int w = threadIdx.x >> 6, j = threadIdx.x & 63;
    int b = blockIdx.x * 4 + w;            // B divisible by 4
    __shared__ float s_qs[4][128];
    __shared__ float s_h[4][64];
    s_qs[w][j] = qstar[b * 128 + j];
    s_qs[w][64 + j] = qstar[b * 128 + 64 + j];
    s_h[w][j] = hh[b * 64 + j];
    __syncthreads();
    float gi = bih[j] + bhh[j];
    float gf = bih[64 + j] + bhh[64 + j];
    float gg = bih[128 + j] + bhh[128 + j];
    float go = bih[192 + j] + bhh[192 + j];
#pragma unroll 4
    for (int i = 0; i < 128; i++) {
        float qv = s_qs[w][i];
        gi += qv * wih[i * 256 + j];
        gf += qv * wih[i * 256 + 64 + j];
        gg += qv * wih[i * 256 + 128 + j];
        go += qv * wih[i * 256 + 192 + j];
    }
#pragma unroll 4
    for (int i = 0; i < 64; i++) {
        float hv = s_h[w][i];
        gi += hv * whh[i * 256 + j];
        gf += hv * whh[i * 256 + 64 + j];
        gg += hv * whh[i * 256 + 128 + j];
        go += hv * whh[i * 256 + 192 + j];
    }
    float c = sigmoidf_(gf) * cc[b * 64 + j] + sigmoidf_(gi) * tanhf(gg);
    float h = sigmoidf_(go) * tanhf(c);
    cc[b * 64 + j] = c;
    hh[b * 64 + j] = h;
    qstar[b * 128 + j] = h;   // q part of next q_star
}

// ---------------- attention + pooling: rvec per batch -> qstar[b][64:128] -----------
__global__ __launch_bounds__(256) void attn_kernel(const float* __restrict__ out,
                                                   const int* __restrict__ batch,
                                                   const float* __restrict__ hh,
                                                   float* __restrict__ qstar, int N) {
    int b = blockIdx.x;
    __shared__ int s_lo, s_hi;
    __shared__ float s_q[64];
    __shared__ float s_red[4];
    __shared__ float s_rv[4][64];
    int t = threadIdx.x;
    if (t == 0) {
        int lo = 0, hi = N;
        while (lo < hi) { int mid = (lo + hi) >> 1; if (batch[mid] < b) lo = mid + 1; else hi = mid; }
        s_lo = lo;
        int lo2 = lo, hi2 = N;
        while (lo2 < hi2) { int mid = (lo2 + hi2) >> 1; if (batch[mid] < b + 1) lo2 = mid + 1; else hi2 = mid; }
        s_hi = lo2;
    }
    if (t < 64) s_q[t] = hh[b * 64 + t];
    __syncthreads();
    int lo = s_lo, hi = s_hi;
    int wave = t >> 6, lane = t & 63;
    float wmax = -3.402823e38f;
    for (int n = lo + wave; n < hi; n += 4) {
        float p = out[(size_t)n * 64 + lane] * s_q[lane];
#pragma unroll
        for (int d = 32; d >= 1; d >>= 1) p += __shfl_xor(p, d);
        wmax = fmaxf(wmax, p);
    }
    if (lane == 0) s_red[wave] = wmax;
    __syncthreads();
    float m = fmaxf(fmaxf(s_red[0], s_red[1]), fmaxf(s_red[2], s_red[3]));
    __syncthreads();
    float ssum = 0.f, rv = 0.f;
    for (int n = lo + wave; n < hi; n += 4) {
        float xv = out[(size_t)n * 64 + lane];
        float p = xv * s_q[lane];
#pragma unroll
        for (int d = 32; d >= 1; d >>= 1) p += __shfl_xor(p, d);
        float a = expf(p - m);
        ssum += a;
        rv += a * xv;
    }
    if (lane == 0) s_red[wave] = ssum;
    s_rv[wave][lane] = rv;
    __syncthreads();
    if (wave == 0) {
        float S = s_red[0] + s_red[1] + s_red[2] + s_red[3];
        float r = s_rv[0][lane] + s_rv[1][lane] + s_rv[2][lane] + s_rv[3][lane];
        qstar[b * 128 + 64 + lane] = (S > 0.f) ? r / S : 0.f;
    }
}

// ---------------- head: y = relu(qstar @ lin1 + b1) @ lin2 + b2 ----------------
__global__ __launch_bounds__(256) void final_kernel(const float* __restrict__ qstar,
                                                    const float* __restrict__ w1,
                                                    const float* __restrict__ b1,
                                                    const float* __restrict__ w2,
                                                    const float* __restrict__ b2,
                                                    float* __restrict__ y) {
    int w = threadIdx.x >> 6, j = threadIdx.x & 63;
    int b = blockIdx.x * 4 + w;
    __shared__ float s_qs[4][128];
    s_qs[w][j] = qstar[b * 128 + j];
    s_qs[w][64 + j] = qstar[b * 128 + 64 + j];
    __syncthreads();
    float tv = b1[j];
#pragma unroll 4
    for (int i = 0; i < 128; i++) tv += s_qs[w][i] * w1[i * 64 + j];
    tv = fmaxf(tv, 0.f);
    float p = tv * w2[j];
#pragma unroll
    for (int d = 32; d >= 1; d >>= 1) p += __shfl_xor(p, d);
    if (j == 0) y[b] = p + b2[0];
}

extern "C" void kernel_launch(void* const* d_in, const int* in_sizes, int n_in,
                              void* d_out, int out_size, void* d_ws, size_t ws_size,
                              hipStream_t stream) {
    const int N = N_NODES, E = N_EDGES, B = N_BATCH;
    const float* x       = (const float*)d_in[0];
    const int*   ei      = (const int*)d_in[1];
    const float* ea      = (const float*)d_in[2];
    const int*   batch   = (const int*)d_in[3];
    const float* lin0_w  = (const float*)d_in[4];
    const float* lin0_b  = (const float*)d_in[5];
    const float* nn1_w   = (const float*)d_in[6];
    const float* nn1_b   = (const float*)d_in[7];
    const float* nn2_w   = (const float*)d_in[8];
    const float* nn2_b   = (const float*)d_in[9];
    const float* root_w  = (const float*)d_in[10];
    const float* root_b  = (const float*)d_in[11];
    const float* gru_wih = (const float*)d_in[12];
    const float* gru_whh = (const float*)d_in[13];
    const float* gru_bih = (const float*)d_in[14];
    const float* gru_bhh = (const float*)d_in[15];
    const float* lstm_wih = (const float*)d_in[16];
    const float* lstm_whh = (const float*)d_in[17];
    const float* lstm_bih = (const float*)d_in[18];
    const float* lstm_bhh = (const float*)d_in[19];
    const float* lin1_w  = (const float*)d_in[20];
    const float* lin1_b  = (const float*)d_in[21];
    const float* lin2_w  = (const float*)d_in[22];
    const float* lin2_b  = (const float*)d_in[23];
    float* y = (float*)d_out;

    char* ws = (char*)d_ws;
    size_t off = 0;
    auto alloc = [&](size_t bytes) { void* p = ws + off; off = (off + bytes + 255) & ~(size_t)255; return p; };
    unsigned short* hb  = (unsigned short*)alloc((size_t)E * 128 * 2);   // 25.6 MB
    unsigned short* bsw = (unsigned short*)alloc((size_t)66048 * 8 * 2); // 1.06 MB
    float* out   = (float*)alloc((size_t)N * 64 * 4);                    // 5.12 MB
    float* agg   = (float*)alloc((size_t)N * 64 * 4);                    // 5.12 MB
    float* deg   = (float*)alloc((size_t)N * 4);
    float* qstar = (float*)alloc((size_t)B * 128 * 4);
    float* hh    = (float*)alloc((size_t)B * 64 * 4);
    float* cc    = (float*)alloc((size_t)B * 64 * 4);

    hipMemsetAsync(deg, 0, (size_t)N * 4, stream);
    deg_kernel<<<(E + 255) / 256, 256, 0, stream>>>(ei, deg, E);
    hidden_kernel<<<E * 128 / 256, 256, 0, stream>>>(ea, nn1_w, nn1_b, hb);
    bsw_pack<<<258, 256, 0, stream>>>(nn2_w, nn2_b, bsw);
    lin0_kernel<<<N * 64 / 256, 256, 0, stream>>>(x, lin0_w, lin0_b, out);

    for (int step = 0; step < 3; ++step) {
        hipMemsetAsync(agg, 0, (size_t)N * 64 * 4, stream);
        msg_mfma<<<(E + 63) / 64, 64, 0, stream>>>(out, hb, bsw, ei, agg, E);
        gru_kernel<<<N / 4, 256, 0, stream>>>(out, agg, deg, root_w, root_b,
                                              gru_wih, gru_whh, gru_bih, gru_bhh);
    }

    hipMemsetAsync(qstar, 0, (size_t)B * 128 * 4, stream);
    hipMemsetAsync(hh, 0, (size_t)B * 64 * 4, stream);
    hipMemsetAsync(cc, 0, (size_t)B * 64 * 4, stream);
    for (int tstep = 0; tstep < 3; ++tstep) {
        lstm_kernel<<<B / 4, 256, 0, stream>>>(qstar, hh, cc, lstm_wih, lstm_whh, lstm_bih, lstm_bhh);
        attn_kernel<<<B, 256, 0, stream>>>(out, batch, hh, qstar, N);
    }
    final_kernel<<<B / 4, 256, 0, stream>>>(qstar, lin1_w, lin1_b, lin2_w, lin2_b, y);
}